// Round 1
// baseline (7513.478 us; speedup 1.0000x reference)
//
#include <hip/hip_runtime.h>

typedef unsigned int u32;
typedef unsigned short u16;
typedef unsigned long long u64;

// ---------- bf16 helpers (manual, RTN-even) ----------
__device__ __forceinline__ u32 f2bf(float f) {
    u32 u = __float_as_uint(f);
    return (u + 0x7fffu + ((u >> 16) & 1u)) >> 16;
}
__device__ __forceinline__ u32 pk(float a, float b) {
    return f2bf(a) | (f2bf(b) << 16);
}
__device__ __forceinline__ float bflo(u32 u) { return __uint_as_float(u << 16); }
__device__ __forceinline__ float bfhi(u32 u) { return __uint_as_float(u & 0xffff0000u); }
__device__ __forceinline__ float bfu(u16 u) { return __uint_as_float(((u32)u) << 16); }

// 4 edges x 4 cols x 2 k fp32 FMA block from packed operands
__device__ __forceinline__ void fma_4e4j(const uint4& mi, const uint4& wq, float (&acc)[4][4]) {
    const u32* mp = (const u32*)&mi;
    const u32* wp = (const u32*)&wq;
    float wl[4], wh[4];
#pragma unroll
    for (int j = 0; j < 4; ++j) { wl[j] = bflo(wp[j]); wh[j] = bfhi(wp[j]); }
#pragma unroll
    for (int e = 0; e < 4; ++e) {
        float ml = bflo(mp[e]), mh = bfhi(mp[e]);
#pragma unroll
        for (int j = 0; j < 4; ++j)
            acc[e][j] = fmaf(mh, wh[j], fmaf(ml, wl[j], acc[e][j]));
    }
}
__device__ __forceinline__ void fma_1e4j(u32 m, const uint4& wq, float (&acc)[4]) {
    const u32* wp = (const u32*)&wq;
    float ml = bflo(m), mh = bfhi(m);
#pragma unroll
    for (int j = 0; j < 4; ++j)
        acc[j] = fmaf(mh, bfhi(wp[j]), fmaf(ml, bflo(wp[j]), acc[j]));
}

// ---------- input projection + LayerNorm + ReLU (wave per node) ----------
__global__ void k_input_proj(const float* __restrict__ x, const float* __restrict__ in_w,
                             const float* __restrict__ in_b, const float* __restrict__ ln_g,
                             const float* __restrict__ ln_b, float* __restrict__ h, int n_nodes) {
    const int lane = threadIdx.x & 63;
    const int node = blockIdx.x * 4 + (threadIdx.x >> 6);
    if (node >= n_nodes) return;
    float acc = in_b[lane];
#pragma unroll
    for (int k = 0; k < 4; ++k) acc = fmaf(x[node * 4 + k], in_w[k * 64 + lane], acc);
    float s = acc;
#pragma unroll
    for (int off = 32; off > 0; off >>= 1) s += __shfl_xor(s, off);
    float mu = s * (1.f / 64.f);
    float d = acc - mu;
    float vs = d * d;
#pragma unroll
    for (int off = 32; off > 0; off >>= 1) vs += __shfl_xor(vs, off);
    float inv = rsqrtf(vs * (1.f / 64.f) + 1e-5f);
    float hv = d * inv * ln_g[lane] + ln_b[lane];
    h[node * 64 + lane] = fmaxf(hv, 0.f);
}

// ---------- edge message MLP + scatter-add ----------
// 64-edge tiles; in-tile sort by type; bf16 LDS staging; fp32 accum; W2 overlays MI region.
__global__ __launch_bounds__(256, 2) void k_edge_mlp(
    const float* __restrict__ h, const int* __restrict__ srcI, const int* __restrict__ dstI,
    const int* __restrict__ etype, const float* __restrict__ w1, const float* __restrict__ b1,
    const float* __restrict__ w2, const float* __restrict__ b2, float* __restrict__ agg,
    int n_edges) {
    __shared__ u32 sW1[2 * 64 * 64];   // [type][kp][j] k-pair packed bf16, 32 KB
    __shared__ u32 sUn[64 * 68];       // MI-T kpacked [kp][edge] (gather) / W2 packed (layer 2), 17 KB
    __shared__ u32 sHT[32 * 68];       // hidden, k-pair packed [kp][edge], 8.5 KB
    __shared__ float sB1[128], sB2[128];
    __shared__ int sSrc[64], sDst[64], sTy[64];

    const int tid = threadIdx.x;
    // stage W1 (both types) + biases once per block
    for (int u = tid; u < 2 * 64 * 64; u += 256) {
        int t = u >> 12, kp = (u >> 6) & 63, j = u & 63;
        const float* wrow = w1 + (t * 128 + 2 * kp) * 64 + j;
        sW1[u] = pk(wrow[0], wrow[64]);
    }
    if (tid < 128) { sB1[tid] = b1[tid]; sB2[tid] = b2[tid]; }

    const int lane = tid & 63;
    const int wv = tid >> 6;
    const int eg = lane >> 4;
    const int jq = lane & 15;
    const int e0 = wv * 16 + eg * 4;
    const int j0 = jq * 4;

    const int n_tiles = (n_edges + 63) >> 6;
    for (int tile = blockIdx.x; tile < n_tiles; tile += gridDim.x) {
        const int base = tile << 6;
        __syncthreads();  // previous tile (and initial staging) complete
        if (tid < 64) {   // wave 0: load meta, sort by type via ballot
            int e = base + tid;
            bool ok = e < n_edges;
            int ty = ok ? (etype[e] & 1) : 1;
            u64 m0 = __ballot(ok && ty == 0);
            u64 lt = (1ull << tid) - 1ull;
            int c0 = __popcll(m0);
            int nlt0 = __popcll(m0 & lt);
            int pos = (ok && ty == 0) ? nlt0 : (c0 + tid - nlt0);
            sSrc[pos] = ok ? srcI[e] : 0;
            sDst[pos] = ok ? dstI[e] : 0;
            sTy[pos] = ty | (ok ? 0 : 2);
        }
        __syncthreads();
        {   // gather [h_src | h_dst] -> sUn (bf16 k-pair transposed)
            const int el = tid >> 2, p = tid & 3;
            const int row = (p < 2) ? sSrc[el] : sDst[el];
            const float4* h4 = (const float4*)h + (size_t)row * 16 + (p & 1) * 8;
            const int kp0 = p * 16;
#pragma unroll
            for (int i = 0; i < 8; ++i) {
                float4 v = h4[i];
                sUn[(kp0 + i * 2) * 68 + el] = pk(v.x, v.y);
                sUn[(kp0 + i * 2 + 1) * 68 + el] = pk(v.z, v.w);
            }
        }
        __syncthreads();
        int tyE[4];
#pragma unroll
        for (int e = 0; e < 4; ++e) tyE[e] = sTy[e0 + e] & 1;
        const bool uni = (tyE[0] == tyE[3]);  // sorted => monotone

        // layer 1: K=128 (64 k-pairs)
        float acc[4][4] = {};
        if (uni) {
            const u32* wb = sW1 + tyE[0] * 4096 + j0;
#pragma unroll 2
            for (int kp = 0; kp < 64; ++kp) {
                uint4 mi = *(const uint4*)(sUn + kp * 68 + e0);
                uint4 wq = *(const uint4*)(wb + kp * 64);
                fma_4e4j(mi, wq, acc);
            }
        } else {
            for (int kp = 0; kp < 64; ++kp) {
                uint4 mi = *(const uint4*)(sUn + kp * 68 + e0);
                const u32* mp = (const u32*)&mi;
#pragma unroll
                for (int e = 0; e < 4; ++e) {
                    uint4 wq = *(const uint4*)(sW1 + tyE[e] * 4096 + kp * 64 + j0);
                    fma_1e4j(mp[e], wq, acc[e]);
                }
            }
        }
        // hidden = relu(acc + b1) -> sHT (k-pair packed)
#pragma unroll
        for (int e = 0; e < 4; ++e) {
            const float* bb = sB1 + tyE[e] * 64 + j0;
            float h0 = fmaxf(acc[e][0] + bb[0], 0.f);
            float h1 = fmaxf(acc[e][1] + bb[1], 0.f);
            float h2 = fmaxf(acc[e][2] + bb[2], 0.f);
            float h3 = fmaxf(acc[e][3] + bb[3], 0.f);
            sHT[(j0 >> 1) * 68 + e0 + e] = pk(h0, h1);
            sHT[((j0 >> 1) + 1) * 68 + e0 + e] = pk(h2, h3);
        }
        __syncthreads();  // sHT ready; sUn (MI) dead
        // restage W2 into sUn region
        for (int u = tid; u < 2 * 32 * 64; u += 256) {
            int t = u >> 11, kp = (u >> 6) & 31, j = u & 63;
            const float* wrow = w2 + (t * 64 + 2 * kp) * 64 + j;
            sUn[u] = pk(wrow[0], wrow[64]);
        }
        __syncthreads();
        // layer 2: K=64 (32 k-pairs)
        float acc2[4][4] = {};
        if (uni) {
            const u32* wb = sUn + tyE[0] * 2048 + j0;
#pragma unroll 2
            for (int kp = 0; kp < 32; ++kp) {
                uint4 mi = *(const uint4*)(sHT + kp * 68 + e0);
                uint4 wq = *(const uint4*)(wb + kp * 64);
                fma_4e4j(mi, wq, acc2);
            }
        } else {
            for (int kp = 0; kp < 32; ++kp) {
                uint4 mi = *(const uint4*)(sHT + kp * 68 + e0);
                const u32* mp = (const u32*)&mi;
#pragma unroll
                for (int e = 0; e < 4; ++e) {
                    uint4 wq = *(const uint4*)(sUn + tyE[e] * 2048 + kp * 64 + j0);
                    fma_1e4j(mp[e], wq, acc2[e]);
                }
            }
        }
        // scatter-add messages
#pragma unroll
        for (int e = 0; e < 4; ++e) {
            if (sTy[e0 + e] & 2) continue;
            const int d = sDst[e0 + e];
            const float* bb = sB2 + tyE[e] * 64 + j0;
            float* ap = agg + (size_t)d * 64 + j0;
#pragma unroll
            for (int j = 0; j < 4; ++j) unsafeAtomicAdd(ap + j, acc2[e][j] + bb[j]);
        }
    }
}

// ---------- GRU gate GEMM: G[n] = [r+z sums (128) | i_n (64) | h_n (64)] in bf16 ----------
__global__ __launch_bounds__(256, 2) void k_gru_gemm(
    const float* __restrict__ agg, const float* __restrict__ h, const float* __restrict__ wi,
    const float* __restrict__ wh, const float* __restrict__ bi, const float* __restrict__ bh,
    u32* __restrict__ G, int n_nodes) {
    __shared__ u32 sR[64 * 128];  // rz block: [kp][c], K=128, 32 KB
    __shared__ u32 sI[32 * 64];   // i_n block: K=64 (agg part)
    __shared__ u32 sH[32 * 64];   // h_n block: K=64 (h part)
    __shared__ u32 sAT[64 * 20];  // A = [agg|h] k-pair packed, 16 nodes
    __shared__ float sBC[256];

    const int tid = threadIdx.x;
    for (int u = tid; u < 64 * 128; u += 256) {
        int kp = u >> 7, c = u & 127;
        int k0 = 2 * kp;
        float v0 = (k0 < 64) ? wi[k0 * 192 + c] : wh[(k0 - 64) * 192 + c];
        float v1 = (k0 + 1 < 64) ? wi[(k0 + 1) * 192 + c] : wh[(k0 + 1 - 64) * 192 + c];
        sR[u] = pk(v0, v1);
    }
    for (int u = tid; u < 32 * 64; u += 256) {
        int kp = u >> 6, c = u & 63;
        sI[u] = pk(wi[(2 * kp) * 192 + 128 + c], wi[(2 * kp + 1) * 192 + 128 + c]);
        sH[u] = pk(wh[(2 * kp) * 192 + 128 + c], wh[(2 * kp + 1) * 192 + 128 + c]);
    }
    if (tid < 256) sBC[tid] = (tid < 128) ? (bi[tid] + bh[tid]) : ((tid < 192) ? bi[tid] : bh[tid - 64]);

    const int jq = tid & 63;
    const int eg = tid >> 6;
    const int n0 = eg * 4;
    const int n_tiles = (n_nodes + 15) >> 4;
    for (int tile = blockIdx.x; tile < n_tiles; tile += gridDim.x) {
        const int nb = tile << 4;
        __syncthreads();
#pragma unroll
        for (int q = 0; q < 4; ++q) {  // stage A (16 nodes x 64 kp)
            int u = tid + q * 256;
            int kp = u >> 4, n = u & 15;
            int node = nb + n;
            float2 v = make_float2(0.f, 0.f);
            if (node < n_nodes) {
                const float* p = (kp < 32) ? (agg + (size_t)node * 64 + 2 * kp)
                                           : (h + (size_t)node * 64 + 2 * kp - 64);
                v = *(const float2*)p;
            }
            sAT[kp * 20 + n] = pk(v.x, v.y);
        }
        __syncthreads();
        float acc[4][4] = {};
        if (jq < 32) {
            const int c0 = jq * 4;
#pragma unroll 2
            for (int kp = 0; kp < 64; ++kp) {
                uint4 mi = *(const uint4*)(sAT + kp * 20 + n0);
                uint4 wq = *(const uint4*)(sR + kp * 128 + c0);
                fma_4e4j(mi, wq, acc);
            }
        } else if (jq < 48) {
            const int c0 = (jq - 32) * 4;
#pragma unroll 2
            for (int kp = 0; kp < 32; ++kp) {
                uint4 mi = *(const uint4*)(sAT + kp * 20 + n0);
                uint4 wq = *(const uint4*)(sI + kp * 64 + c0);
                fma_4e4j(mi, wq, acc);
            }
        } else {
            const int c0 = (jq - 48) * 4;
#pragma unroll 2
            for (int kp = 0; kp < 32; ++kp) {
                uint4 mi = *(const uint4*)(sAT + (32 + kp) * 20 + n0);
                uint4 wq = *(const uint4*)(sH + kp * 64 + c0);
                fma_4e4j(mi, wq, acc);
            }
        }
        const int cbase = (jq < 32) ? jq * 4 : ((jq < 48) ? 128 + (jq - 32) * 4 : 192 + (jq - 48) * 4);
#pragma unroll
        for (int n = 0; n < 4; ++n) {
            int node = nb + n0 + n;
            if (node >= n_nodes) continue;
            float v0 = acc[n][0] + sBC[cbase + 0];
            float v1 = acc[n][1] + sBC[cbase + 1];
            float v2 = acc[n][2] + sBC[cbase + 2];
            float v3 = acc[n][3] + sBC[cbase + 3];
            u32* gp = G + (size_t)node * 128 + (cbase >> 1);
            gp[0] = pk(v0, v1);
            gp[1] = pk(v2, v3);
        }
    }
}

// ---------- GRU elementwise combine (in-place h update) ----------
__global__ void k_gru_combine(const u16* __restrict__ G16, float* __restrict__ h, int n_nodes) {
    int gid = blockIdx.x * 256 + threadIdx.x;
    int node = gid >> 6, j = gid & 63;
    if (node >= n_nodes) return;
    const u16* g = G16 + (size_t)node * 256;
    float rs = bfu(g[j]), zs = bfu(g[64 + j]), in_ = bfu(g[128 + j]), hn = bfu(g[192 + j]);
    float r = 1.f / (1.f + __expf(-rs));
    float z = 1.f / (1.f + __expf(-zs));
    float nn = tanhf(fmaf(r, hn, in_));
    float hv = h[(size_t)node * 64 + j];
    h[(size_t)node * 64 + j] = (1.f - z) * nn + z * hv;
}

// ---------- readout + data-qubit correction (wave per node) ----------
__global__ void k_readout(const float* __restrict__ h, const float* __restrict__ x,
                          const int* __restrict__ node_type, const float* __restrict__ w1,
                          const float* __restrict__ b1, const float* __restrict__ w2,
                          const float* __restrict__ b2, float* __restrict__ out, int n_nodes) {
    const int lane = threadIdx.x & 63;
    const int node = blockIdx.x * 4 + (threadIdx.x >> 6);
    if (node >= n_nodes) return;
    float hv = h[(size_t)node * 64 + lane];
    float acc = b1[lane];
    for (int k = 0; k < 64; ++k) acc = fmaf(__shfl(hv, k), w1[k * 64 + lane], acc);
    float t = fmaxf(acc, 0.f) * w2[lane];
#pragma unroll
    for (int off = 32; off > 0; off >>= 1) t += __shfl_xor(t, off);
    if (lane == 0) {
        float o = t + b2[0];
        out[node] = (node_type[node] == 0) ? (x[node * 4] + o) : 0.f;
    }
}

extern "C" void kernel_launch(void* const* d_in, const int* in_sizes, int n_in, void* d_out,
                              int out_size, void* d_ws, size_t ws_size, hipStream_t stream) {
    const float* x = (const float*)d_in[0];
    const int* node_type = (const int*)d_in[1];
    const int* edge_index = (const int*)d_in[2];
    const int* edge_type = (const int*)d_in[3];
    const float* in_w = (const float*)d_in[4];
    const float* in_b = (const float*)d_in[5];
    const float* ln_g = (const float*)d_in[6];
    const float* ln_b = (const float*)d_in[7];
    const float* mlp_w1 = (const float*)d_in[8];
    const float* mlp_b1 = (const float*)d_in[9];
    const float* mlp_w2 = (const float*)d_in[10];
    const float* mlp_b2 = (const float*)d_in[11];
    const float* gru_wi = (const float*)d_in[12];
    const float* gru_wh = (const float*)d_in[13];
    const float* gru_bi = (const float*)d_in[14];
    const float* gru_bh = (const float*)d_in[15];
    const float* ro_w1 = (const float*)d_in[16];
    const float* ro_b1 = (const float*)d_in[17];
    const float* ro_w2 = (const float*)d_in[18];
    const float* ro_b2 = (const float*)d_in[19];

    const int N = in_sizes[1];   // nodes
    const int M = in_sizes[3];   // edges
    const int* src = edge_index;
    const int* dst = edge_index + M;

    // workspace: h (N*256 B) | agg (N*256 B) | G (N*512 B bf16)
    float* h = (float*)d_ws;
    float* agg = (float*)((char*)d_ws + (size_t)N * 256);
    u32* G = (u32*)((char*)d_ws + (size_t)N * 512);

    k_input_proj<<<(N + 3) / 4, 256, 0, stream>>>(x, in_w, in_b, ln_g, ln_b, h, N);
    for (int l = 0; l < 3; ++l) {
        hipMemsetAsync(agg, 0, (size_t)N * 64 * sizeof(float), stream);
        k_edge_mlp<<<512, 256, 0, stream>>>(h, src, dst, edge_type,
                                            mlp_w1 + (size_t)l * 2 * 128 * 64,
                                            mlp_b1 + (size_t)l * 2 * 64,
                                            mlp_w2 + (size_t)l * 2 * 64 * 64,
                                            mlp_b2 + (size_t)l * 2 * 64, agg, M);
        k_gru_gemm<<<512, 256, 0, stream>>>(agg, h, gru_wi + (size_t)l * 64 * 192,
                                            gru_wh + (size_t)l * 64 * 192,
                                            gru_bi + (size_t)l * 192, gru_bh + (size_t)l * 192,
                                            G, N);
        k_gru_combine<<<(N * 64 + 255) / 256, 256, 0, stream>>>((const u16*)G, h, N);
    }
    k_readout<<<(N + 3) / 4, 256, 0, stream>>>(h, x, node_type, ro_w1, ro_b1, ro_w2, ro_b2,
                                               (float*)d_out, N);
}

// Round 2
// 7374.721 us; speedup vs baseline: 1.0188x; 1.0188x over previous
//
#include <hip/hip_runtime.h>

typedef unsigned int u32;
typedef unsigned short u16;
typedef unsigned long long u64;

// ---------- bf16 helpers (manual, RTN-even) ----------
__device__ __forceinline__ u32 f2bf(float f) {
    u32 u = __float_as_uint(f);
    return (u + 0x7fffu + ((u >> 16) & 1u)) >> 16;
}
__device__ __forceinline__ u32 pk(float a, float b) {
    return f2bf(a) | (f2bf(b) << 16);
}
__device__ __forceinline__ float bflo(u32 u) { return __uint_as_float(u << 16); }
__device__ __forceinline__ float bfhi(u32 u) { return __uint_as_float(u & 0xffff0000u); }
__device__ __forceinline__ float bfu(u16 u) { return __uint_as_float(((u32)u) << 16); }

// 4 edges x 4 cols x 2 k fp32 FMA block from packed operands
__device__ __forceinline__ void fma_4e4j(const uint4& mi, const uint4& wq, float (&acc)[4][4]) {
    const u32* mp = (const u32*)&mi;
    const u32* wp = (const u32*)&wq;
    float wl[4], wh[4];
#pragma unroll
    for (int j = 0; j < 4; ++j) { wl[j] = bflo(wp[j]); wh[j] = bfhi(wp[j]); }
#pragma unroll
    for (int e = 0; e < 4; ++e) {
        float ml = bflo(mp[e]), mh = bfhi(mp[e]);
#pragma unroll
        for (int j = 0; j < 4; ++j)
            acc[e][j] = fmaf(mh, wh[j], fmaf(ml, wl[j], acc[e][j]));
    }
}
__device__ __forceinline__ void fma_1e4j(u32 m, const uint4& wq, float (&acc)[4]) {
    const u32* wp = (const u32*)&wq;
    float ml = bflo(m), mh = bfhi(m);
#pragma unroll
    for (int j = 0; j < 4; ++j)
        acc[j] = fmaf(mh, bfhi(wp[j]), fmaf(ml, bflo(wp[j]), acc[j]));
}

// ---------- input projection + LayerNorm + ReLU (wave per node) ----------
__global__ void k_input_proj(const float* __restrict__ x, const float* __restrict__ in_w,
                             const float* __restrict__ in_b, const float* __restrict__ ln_g,
                             const float* __restrict__ ln_b, float* __restrict__ h, int n_nodes) {
    const int lane = threadIdx.x & 63;
    const int node = blockIdx.x * 4 + (threadIdx.x >> 6);
    if (node >= n_nodes) return;
    float acc = in_b[lane];
#pragma unroll
    for (int k = 0; k < 4; ++k) acc = fmaf(x[node * 4 + k], in_w[k * 64 + lane], acc);
    float s = acc;
#pragma unroll
    for (int off = 32; off > 0; off >>= 1) s += __shfl_xor(s, off);
    float mu = s * (1.f / 64.f);
    float d = acc - mu;
    float vs = d * d;
#pragma unroll
    for (int off = 32; off > 0; off >>= 1) vs += __shfl_xor(vs, off);
    float inv = rsqrtf(vs * (1.f / 64.f) + 1e-5f);
    float hv = d * inv * ln_g[lane] + ln_b[lane];
    h[node * 64 + lane] = fmaxf(hv, 0.f);
}

// ---------- dst-sort: histogram, scan, scatter ----------
__global__ void k_hist(const int* __restrict__ dst, int* __restrict__ cnt, int M) {
    int i = blockIdx.x * 256 + threadIdx.x;
    if (i < M) atomicAdd(&cnt[dst[i]], 1);
}

__global__ void k_scan1(int* __restrict__ data, int* __restrict__ part, int N) {
    __shared__ int s[1024];
    const int t = threadIdx.x;
    const int i = blockIdx.x * 1024 + t;
    int v = (i < N) ? data[i] : 0;
    s[t] = v;
    __syncthreads();
#pragma unroll
    for (int d = 1; d < 1024; d <<= 1) {
        int x = (t >= d) ? s[t - d] : 0;
        __syncthreads();
        s[t] += x;
        __syncthreads();
    }
    if (i < N) data[i] = s[t] - v;  // exclusive
    if (t == 1023) part[blockIdx.x] = s[1023];
}

__global__ void k_scan2(int* __restrict__ part, int nb) {
    if (threadIdx.x == 0 && blockIdx.x == 0) {
        int a = 0;
        for (int i = 0; i < nb; ++i) { int t = part[i]; part[i] = a; a += t; }
    }
}

__global__ void k_scan3(int* __restrict__ data, const int* __restrict__ part, int N) {
    int i = blockIdx.x * 1024 + threadIdx.x;
    if (i < N) data[i] += part[blockIdx.x];
}

__global__ void k_scatter(const int* __restrict__ src, const int* __restrict__ dst,
                          const int* __restrict__ ety, int* __restrict__ cursor,
                          int* __restrict__ srcP, int* __restrict__ dstP, int M) {
    int e = blockIdx.x * 256 + threadIdx.x;
    if (e < M) {
        int d = dst[e];
        int pos = atomicAdd(&cursor[d], 1);
        srcP[pos] = src[e] | ((ety[e] & 1) << 30);
        dstP[pos] = d;
    }
}

// ---------- edge message MLP + run-reduced scatter-add ----------
// Edges pre-sorted by dst. 64-edge tiles; in-tile ballot-sort by type for compute;
// messages written back to LDS in original (dst-sorted) order; per-run reduction
// -> one atomic per (run-segment, column) instead of per (edge, column).
__global__ __launch_bounds__(256, 2) void k_edge_mlp(
    const float* __restrict__ h, const int* __restrict__ srcP, const int* __restrict__ dstP,
    const float* __restrict__ w1, const float* __restrict__ b1,
    const float* __restrict__ w2, const float* __restrict__ b2, float* __restrict__ agg,
    int n_edges) {
    __shared__ u32 sW1[2 * 64 * 64];   // [type][kp][j] k-pair packed bf16, 32 KB
    __shared__ u32 sUn[64 * 69];       // MI-T kpacked (gather) / W2 packed / msgF fp32, 17.25 KB
    __shared__ u32 sHT[32 * 68];       // hidden, k-pair packed [kp][edge], 8.5 KB
    __shared__ float sB1[128], sB2[128];
    __shared__ int sSrcS[64], sDstS[64], sTyS[64], sOrig[64], sDstO[64];

    const int tid = threadIdx.x;
    for (int u = tid; u < 2 * 64 * 64; u += 256) {
        int t = u >> 12, kp = (u >> 6) & 63, j = u & 63;
        const float* wrow = w1 + (t * 128 + 2 * kp) * 64 + j;
        sW1[u] = pk(wrow[0], wrow[64]);
    }
    if (tid < 128) { sB1[tid] = b1[tid]; sB2[tid] = b2[tid]; }

    const int lane = tid & 63;
    const int wv = tid >> 6;
    const int eg = lane >> 4;
    const int jq = lane & 15;
    const int e0 = wv * 16 + eg * 4;
    const int j0 = jq * 4;

    const int n_tiles = (n_edges + 63) >> 6;
    for (int tile = blockIdx.x; tile < n_tiles; tile += gridDim.x) {
        const int base = tile << 6;
        __syncthreads();  // previous tile complete
        if (tid < 64) {   // wave 0: load meta (sorted-by-dst order), ballot-sort by type
            int e = base + tid;
            bool ok = e < n_edges;
            u32 sp = ok ? (u32)srcP[e] : 0u;
            int ty = ok ? (int)((sp >> 30) & 1u) : 1;
            int sr = (int)(sp & 0x3FFFFFFFu);
            int d = ok ? dstP[e] : -1;
            u64 m0 = __ballot(ok && ty == 0);
            u64 lt = (1ull << tid) - 1ull;
            int c0 = __popcll(m0);
            int nlt0 = __popcll(m0 & lt);
            int pos = (ok && ty == 0) ? nlt0 : (c0 + tid - nlt0);
            sSrcS[pos] = ok ? sr : 0;
            sDstS[pos] = ok ? d : 0;
            sTyS[pos] = ty | (ok ? 0 : 2);
            sOrig[pos] = tid;
            sDstO[tid] = ok ? d : -1;
        }
        __syncthreads();
        {   // gather [h_src | h_dst] -> sUn (bf16 k-pair transposed, stride 69)
            const int el = tid >> 2, p = tid & 3;
            const int row = (p < 2) ? sSrcS[el] : sDstS[el];
            const float4* h4 = (const float4*)h + (size_t)row * 16 + (p & 1) * 8;
            const int kp0 = p * 16;
#pragma unroll
            for (int i = 0; i < 8; ++i) {
                float4 v = h4[i];
                sUn[(kp0 + i * 2) * 69 + el] = pk(v.x, v.y);
                sUn[(kp0 + i * 2 + 1) * 69 + el] = pk(v.z, v.w);
            }
        }
        __syncthreads();
        int tyE[4];
#pragma unroll
        for (int e = 0; e < 4; ++e) tyE[e] = sTyS[e0 + e] & 1;
        const bool uni = (tyE[0] == tyE[3]);  // sorted => monotone

        // layer 1: K=128 (64 k-pairs)
        float acc[4][4] = {};
        if (uni) {
            const u32* wb = sW1 + tyE[0] * 4096 + j0;
#pragma unroll 2
            for (int kp = 0; kp < 64; ++kp) {
                uint4 mi = *(const uint4*)(sUn + kp * 69 + e0);
                uint4 wq = *(const uint4*)(wb + kp * 64);
                fma_4e4j(mi, wq, acc);
            }
        } else {
            for (int kp = 0; kp < 64; ++kp) {
                uint4 mi = *(const uint4*)(sUn + kp * 69 + e0);
                const u32* mp = (const u32*)&mi;
#pragma unroll
                for (int e = 0; e < 4; ++e) {
                    uint4 wq = *(const uint4*)(sW1 + tyE[e] * 4096 + kp * 64 + j0);
                    fma_1e4j(mp[e], wq, acc[e]);
                }
            }
        }
        // hidden = relu(acc + b1) -> sHT (k-pair packed)
#pragma unroll
        for (int e = 0; e < 4; ++e) {
            const float* bb = sB1 + tyE[e] * 64 + j0;
            float h0 = fmaxf(acc[e][0] + bb[0], 0.f);
            float h1 = fmaxf(acc[e][1] + bb[1], 0.f);
            float h2 = fmaxf(acc[e][2] + bb[2], 0.f);
            float h3 = fmaxf(acc[e][3] + bb[3], 0.f);
            sHT[(j0 >> 1) * 68 + e0 + e] = pk(h0, h1);
            sHT[((j0 >> 1) + 1) * 68 + e0 + e] = pk(h2, h3);
        }
        __syncthreads();  // sHT ready; sUn (MI) dead
        // restage W2 into sUn region
        for (int u = tid; u < 2 * 32 * 64; u += 256) {
            int t = u >> 11, kp = (u >> 6) & 31, j = u & 63;
            const float* wrow = w2 + (t * 64 + 2 * kp) * 64 + j;
            sUn[u] = pk(wrow[0], wrow[64]);
        }
        __syncthreads();
        // layer 2: K=64 (32 k-pairs)
        float acc2[4][4] = {};
        if (uni) {
            const u32* wb = sUn + tyE[0] * 2048 + j0;
#pragma unroll 2
            for (int kp = 0; kp < 32; ++kp) {
                uint4 mi = *(const uint4*)(sHT + kp * 68 + e0);
                uint4 wq = *(const uint4*)(wb + kp * 64);
                fma_4e4j(mi, wq, acc2);
            }
        } else {
            for (int kp = 0; kp < 32; ++kp) {
                uint4 mi = *(const uint4*)(sHT + kp * 68 + e0);
                const u32* mp = (const u32*)&mi;
#pragma unroll
                for (int e = 0; e < 4; ++e) {
                    uint4 wq = *(const uint4*)(sUn + tyE[e] * 2048 + kp * 64 + j0);
                    fma_1e4j(mp[e], wq, acc2[e]);
                }
            }
        }
        __syncthreads();  // all W2 reads done; sUn -> msgF fp32 [col][origRow], stride 69
        {
            float* mf = (float*)sUn;
#pragma unroll
            for (int e = 0; e < 4; ++e) {
                int sp = e0 + e;
                if (sTyS[sp] & 2) continue;
                const int orow = sOrig[sp];
                const float* bb = sB2 + (sTyS[sp] & 1) * 64 + j0;
#pragma unroll
                for (int j = 0; j < 4; ++j) mf[(j0 + j) * 69 + orow] = acc2[e][j] + bb[j];
            }
        }
        __syncthreads();
        {   // run-reduction in dst-sorted order: 64 cols x 4 chunks of 16 edges
            const float* mf = (const float*)sUn;
            const int c = tid & 63, q = tid >> 6;
            float a = 0.f;
            int cur = -1;
            for (int i = 0; i < 16; ++i) {
                int e = q * 16 + i;
                int d = sDstO[e];
                if (d != cur) {
                    if (cur >= 0) unsafeAtomicAdd(agg + (size_t)cur * 64 + c, a);
                    cur = d; a = 0.f;
                }
                if (d >= 0) a += mf[c * 69 + e];
            }
            if (cur >= 0) unsafeAtomicAdd(agg + (size_t)cur * 64 + c, a);
        }
    }
}

// ---------- GRU gate GEMM + fused elementwise combine (in-place h update) ----------
__global__ __launch_bounds__(256, 2) void k_gru_gemm(
    const float* __restrict__ agg, float* __restrict__ h, const float* __restrict__ wi,
    const float* __restrict__ wh, const float* __restrict__ bi, const float* __restrict__ bh,
    int n_nodes) {
    __shared__ u32 sR[64 * 128];  // rz block: [kp][c], K=128, 32 KB
    __shared__ u32 sI[32 * 64];   // i_n block: K=64 (agg part)
    __shared__ u32 sH[32 * 64];   // h_n block: K=64 (h part)
    __shared__ u32 sAT[64 * 20];  // A = [agg|h] k-pair packed, 16 nodes
    __shared__ u32 sG[16 * 128];  // gate pre-activations, bf16 pairs [node][pair]
    __shared__ float sBC[256];

    const int tid = threadIdx.x;
    for (int u = tid; u < 64 * 128; u += 256) {
        int kp = u >> 7, c = u & 127;
        int k0 = 2 * kp;
        float v0 = (k0 < 64) ? wi[k0 * 192 + c] : wh[(k0 - 64) * 192 + c];
        float v1 = (k0 + 1 < 64) ? wi[(k0 + 1) * 192 + c] : wh[(k0 + 1 - 64) * 192 + c];
        sR[u] = pk(v0, v1);
    }
    for (int u = tid; u < 32 * 64; u += 256) {
        int kp = u >> 6, c = u & 63;
        sI[u] = pk(wi[(2 * kp) * 192 + 128 + c], wi[(2 * kp + 1) * 192 + 128 + c]);
        sH[u] = pk(wh[(2 * kp) * 192 + 128 + c], wh[(2 * kp + 1) * 192 + 128 + c]);
    }
    if (tid < 256) sBC[tid] = (tid < 128) ? (bi[tid] + bh[tid]) : ((tid < 192) ? bi[tid] : bh[tid - 64]);

    const int jq = tid & 63;
    const int eg = tid >> 6;
    const int n0 = eg * 4;
    const int n_tiles = (n_nodes + 15) >> 4;
    for (int tile = blockIdx.x; tile < n_tiles; tile += gridDim.x) {
        const int nb = tile << 4;
        __syncthreads();
#pragma unroll
        for (int q = 0; q < 4; ++q) {  // stage A (16 nodes x 64 kp)
            int u = tid + q * 256;
            int kp = u >> 4, n = u & 15;
            int node = nb + n;
            float2 v = make_float2(0.f, 0.f);
            if (node < n_nodes) {
                const float* p = (kp < 32) ? (agg + (size_t)node * 64 + 2 * kp)
                                           : (h + (size_t)node * 64 + 2 * kp - 64);
                v = *(const float2*)p;
            }
            sAT[kp * 20 + n] = pk(v.x, v.y);
        }
        __syncthreads();
        float acc[4][4] = {};
        if (jq < 32) {
            const int c0 = jq * 4;
#pragma unroll 2
            for (int kp = 0; kp < 64; ++kp) {
                uint4 mi = *(const uint4*)(sAT + kp * 20 + n0);
                uint4 wq = *(const uint4*)(sR + kp * 128 + c0);
                fma_4e4j(mi, wq, acc);
            }
        } else if (jq < 48) {
            const int c0 = (jq - 32) * 4;
#pragma unroll 2
            for (int kp = 0; kp < 32; ++kp) {
                uint4 mi = *(const uint4*)(sAT + kp * 20 + n0);
                uint4 wq = *(const uint4*)(sI + kp * 64 + c0);
                fma_4e4j(mi, wq, acc);
            }
        } else {
            const int c0 = (jq - 48) * 4;
#pragma unroll 2
            for (int kp = 0; kp < 32; ++kp) {
                uint4 mi = *(const uint4*)(sAT + (32 + kp) * 20 + n0);
                uint4 wq = *(const uint4*)(sH + kp * 64 + c0);
                fma_4e4j(mi, wq, acc);
            }
        }
        const int cbase = (jq < 32) ? jq * 4 : ((jq < 48) ? 128 + (jq - 32) * 4 : 192 + (jq - 48) * 4);
#pragma unroll
        for (int n = 0; n < 4; ++n) {
            int node = nb + n0 + n;
            if (node >= n_nodes) continue;
            float v0 = acc[n][0] + sBC[cbase + 0];
            float v1 = acc[n][1] + sBC[cbase + 1];
            float v2 = acc[n][2] + sBC[cbase + 2];
            float v3 = acc[n][3] + sBC[cbase + 3];
            u32* gp = sG + (n0 + n) * 128 + (cbase >> 1);
            gp[0] = pk(v0, v1);
            gp[1] = pk(v2, v3);
        }
        __syncthreads();
        // fused GRU combine: 16 nodes x 64 cols
        const u16* g16 = (const u16*)sG;
#pragma unroll
        for (int qq = 0; qq < 4; ++qq) {
            int idx = tid + qq * 256;
            int nl = idx >> 6, j = idx & 63;
            int node = nb + nl;
            if (node < n_nodes) {
                const u16* g = g16 + nl * 256;
                float rs = bfu(g[j]), zs = bfu(g[64 + j]), in_ = bfu(g[128 + j]), hn = bfu(g[192 + j]);
                float r = 1.f / (1.f + __expf(-rs));
                float z = 1.f / (1.f + __expf(-zs));
                float nn2 = tanhf(fmaf(r, hn, in_));
                float hv = h[(size_t)node * 64 + j];
                h[(size_t)node * 64 + j] = (1.f - z) * nn2 + z * hv;
            }
        }
    }
}

// ---------- readout + data-qubit correction (wave per node) ----------
__global__ void k_readout(const float* __restrict__ h, const float* __restrict__ x,
                          const int* __restrict__ node_type, const float* __restrict__ w1,
                          const float* __restrict__ b1, const float* __restrict__ w2,
                          const float* __restrict__ b2, float* __restrict__ out, int n_nodes) {
    const int lane = threadIdx.x & 63;
    const int node = blockIdx.x * 4 + (threadIdx.x >> 6);
    if (node >= n_nodes) return;
    float hv = h[(size_t)node * 64 + lane];
    float acc = b1[lane];
    for (int k = 0; k < 64; ++k) acc = fmaf(__shfl(hv, k), w1[k * 64 + lane], acc);
    float t = fmaxf(acc, 0.f) * w2[lane];
#pragma unroll
    for (int off = 32; off > 0; off >>= 1) t += __shfl_xor(t, off);
    if (lane == 0) {
        float o = t + b2[0];
        out[node] = (node_type[node] == 0) ? (x[node * 4] + o) : 0.f;
    }
}

extern "C" void kernel_launch(void* const* d_in, const int* in_sizes, int n_in, void* d_out,
                              int out_size, void* d_ws, size_t ws_size, hipStream_t stream) {
    const float* x = (const float*)d_in[0];
    const int* node_type = (const int*)d_in[1];
    const int* edge_index = (const int*)d_in[2];
    const int* edge_type = (const int*)d_in[3];
    const float* in_w = (const float*)d_in[4];
    const float* in_b = (const float*)d_in[5];
    const float* ln_g = (const float*)d_in[6];
    const float* ln_b = (const float*)d_in[7];
    const float* mlp_w1 = (const float*)d_in[8];
    const float* mlp_b1 = (const float*)d_in[9];
    const float* mlp_w2 = (const float*)d_in[10];
    const float* mlp_b2 = (const float*)d_in[11];
    const float* gru_wi = (const float*)d_in[12];
    const float* gru_wh = (const float*)d_in[13];
    const float* gru_bi = (const float*)d_in[14];
    const float* gru_bh = (const float*)d_in[15];
    const float* ro_w1 = (const float*)d_in[16];
    const float* ro_b1 = (const float*)d_in[17];
    const float* ro_w2 = (const float*)d_in[18];
    const float* ro_b2 = (const float*)d_in[19];

    const int N = in_sizes[1];  // nodes
    const int M = in_sizes[3];  // edges
    const int* src = edge_index;
    const int* dst = edge_index + M;

    // ws layout: h (N*256B) | agg (N*256B) | off (512KB region) | part | srcP (M*4) | dstP (M*4)
    float* h = (float*)d_ws;
    float* agg = (float*)((char*)d_ws + (size_t)N * 256);
    int* off = (int*)((char*)d_ws + (size_t)N * 512);
    int* part = (int*)((char*)d_ws + (size_t)N * 512 + 512 * 1024);
    int* srcP = (int*)((char*)d_ws + (size_t)N * 512 + 1024 * 1024);
    int* dstP = srcP + M;

    const int nb = (N + 1023) / 1024;

    // build dst-sorted edge permutation (once per call, reused by all 3 layers)
    hipMemsetAsync(off, 0, (size_t)N * sizeof(int), stream);
    k_hist<<<(M + 255) / 256, 256, 0, stream>>>(dst, off, M);
    k_scan1<<<nb, 1024, 0, stream>>>(off, part, N);
    k_scan2<<<1, 64, 0, stream>>>(part, nb);
    k_scan3<<<nb, 1024, 0, stream>>>(off, part, N);
    k_scatter<<<(M + 255) / 256, 256, 0, stream>>>(src, dst, edge_type, off, srcP, dstP, M);

    k_input_proj<<<(N + 3) / 4, 256, 0, stream>>>(x, in_w, in_b, ln_g, ln_b, h, N);
    for (int l = 0; l < 3; ++l) {
        hipMemsetAsync(agg, 0, (size_t)N * 64 * sizeof(float), stream);
        k_edge_mlp<<<512, 256, 0, stream>>>(h, srcP, dstP,
                                            mlp_w1 + (size_t)l * 2 * 128 * 64,
                                            mlp_b1 + (size_t)l * 2 * 64,
                                            mlp_w2 + (size_t)l * 2 * 64 * 64,
                                            mlp_b2 + (size_t)l * 2 * 64, agg, M);
        k_gru_gemm<<<512, 256, 0, stream>>>(agg, h, gru_wi + (size_t)l * 64 * 192,
                                            gru_wh + (size_t)l * 64 * 192,
                                            gru_bi + (size_t)l * 192, gru_bh + (size_t)l * 192, N);
    }
    k_readout<<<(N + 3) / 4, 256, 0, stream>>>(h, x, node_type, ro_w1, ro_b1, ro_w2, ro_b2,
                                               (float*)d_out, N);
}